// Round 4
// baseline (212.564 us; speedup 1.0000x reference)
//
#include <hip/hip_runtime.h>

#define N_NODES 65536
#define D_FEAT  64

// ---------- workspace layout ----------
// cursor  : int[N_NODES]      @ 0        (256 KB)  counts -> scatter cursor
// offsets : int[N_NODES+1]    @ 0x40000  (256 KB + 4)
// bsums   : int[256]          @ 0x80100
// eidx    : int[n_edges]      @ 0x100000 (4 MB)    CSR-ordered edge indices

// Phase 1: histogram of row ids (4 edges/thread via int4)
__global__ void hist_kernel(const int* __restrict__ row, int* __restrict__ counts, int n) {
    int i4 = blockIdx.x * blockDim.x + threadIdx.x;
    int base = i4 * 4;
    if (base + 3 < n) {
        int4 r = reinterpret_cast<const int4*>(row)[i4];
        atomicAdd(&counts[r.x], 1);
        atomicAdd(&counts[r.y], 1);
        atomicAdd(&counts[r.z], 1);
        atomicAdd(&counts[r.w], 1);
    } else {
        for (int i = base; i < n; ++i) atomicAdd(&counts[row[i]], 1);
    }
}

// Phase 2a: per-block exclusive scan of 256 counts; emit block sums.
__global__ void scan_local_kernel(const int* __restrict__ counts, int* __restrict__ offsets,
                                  int* __restrict__ bsums) {
    __shared__ int sh[256];
    int t = threadIdx.x;
    int i = blockIdx.x * 256 + t;
    int c = counts[i];
    sh[t] = c;
    __syncthreads();
    for (int d = 1; d < 256; d <<= 1) {
        int add = (t >= d) ? sh[t - d] : 0;
        __syncthreads();
        sh[t] += add;
        __syncthreads();
    }
    offsets[i] = sh[t] - c;                  // exclusive within block
    if (t == 255) bsums[blockIdx.x] = sh[255];
}

// Phase 2b: exclusive scan of the 256 block sums.
__global__ void scan_bsums_kernel(int* __restrict__ bsums) {
    __shared__ int sh[256];
    int t = threadIdx.x;
    int c = bsums[t];
    sh[t] = c;
    __syncthreads();
    for (int d = 1; d < 256; d <<= 1) {
        int add = (t >= d) ? sh[t - d] : 0;
        __syncthreads();
        sh[t] += add;
        __syncthreads();
    }
    bsums[t] = sh[t] - c;                    // exclusive
}

// Phase 2c: add block prefix; init cursor; finalize offsets[N]=E.
__global__ void scan_add_kernel(int* __restrict__ offsets, const int* __restrict__ bsums,
                                int* __restrict__ cursor, int n_edges) {
    int i = blockIdx.x * 256 + threadIdx.x;
    int off = offsets[i] + bsums[blockIdx.x];
    offsets[i] = off;
    cursor[i] = off;
    if (i == 0) offsets[N_NODES] = n_edges;
}

// Phase 3: scatter edge INDEX (4B) into CSR order. 1 edge/thread (occupancy).
// Scattered footprint = 4 MB (vs 8 MB pairs) -> ~halves the per-XCD L2
// dirty-line writeback amplification.
__global__ void scatter_kernel(const int* __restrict__ row, int* __restrict__ cursor,
                               int* __restrict__ eidx, int n) {
    int i = blockIdx.x * blockDim.x + threadIdx.x;
    if (i < n) {
        int pos = atomicAdd(&cursor[row[i]], 1);
        __builtin_nontemporal_store(i, &eidx[pos]);
    }
}

// Phase 4: CSR SpMM — one 64-lane wave per row, lane = feature dim, unroll 4.
// col/val reads are wave-uniform 4B loads into 4MB L2-resident arrays.
__global__ void spmm_csr_kernel(const float* __restrict__ x, const int* __restrict__ offsets,
                                const int* __restrict__ eidx, const int* __restrict__ col,
                                const float* __restrict__ val, float* __restrict__ out) {
    int gid = blockIdx.x * blockDim.x + threadIdx.x;
    int r = gid >> 6;
    int lane = gid & 63;
    if (r >= N_NODES) return;
    int beg = offsets[r], end = offsets[r + 1];
    float acc = 0.f;
    int e = beg;
    for (; e + 4 <= end; e += 4) {
        int i0 = eidx[e + 0], i1 = eidx[e + 1], i2 = eidx[e + 2], i3 = eidx[e + 3];
        int c0 = col[i0], c1 = col[i1], c2 = col[i2], c3 = col[i3];
        float v0 = val[i0], v1 = val[i1], v2 = val[i2], v3 = val[i3];
        float x0 = x[(size_t)c0 * D_FEAT + lane];
        float x1 = x[(size_t)c1 * D_FEAT + lane];
        float x2 = x[(size_t)c2 * D_FEAT + lane];
        float x3 = x[(size_t)c3 * D_FEAT + lane];
        acc += v0 * x0;
        acc += v1 * x1;
        acc += v2 * x2;
        acc += v3 * x3;
    }
    for (; e < end; ++e) {
        int i0 = eidx[e];
        acc += val[i0] * x[(size_t)col[i0] * D_FEAT + lane];
    }
    out[(size_t)r * D_FEAT + lane] = acc;
}

// Fallback (ws too small): atomic COO
__global__ void spmm_atomic_kernel(const float* __restrict__ x, const int* __restrict__ row,
                                   const int* __restrict__ col, const float* __restrict__ val,
                                   float* __restrict__ out, int n_edges) {
    int gid = blockIdx.x * blockDim.x + threadIdx.x;
    int e = gid >> 6;
    int lane = gid & 63;
    if (e >= n_edges) return;
    atomicAdd(&out[(size_t)row[e] * D_FEAT + lane], val[e] * x[(size_t)col[e] * D_FEAT + lane]);
}

extern "C" void kernel_launch(void* const* d_in, const int* in_sizes, int n_in,
                              void* d_out, int out_size, void* d_ws, size_t ws_size,
                              hipStream_t stream) {
    const float* x   = (const float*)d_in[0];
    const int*   row = (const int*)d_in[1];
    const int*   col = (const int*)d_in[2];
    const float* val = (const float*)d_in[3];
    float* out = (float*)d_out;
    int n_edges = in_sizes[1];

    size_t need = 0x100000 + (size_t)n_edges * sizeof(int);
    if (ws_size < need) {
        hipMemsetAsync(d_out, 0, (size_t)out_size * sizeof(float), stream);
        int blocks = (n_edges * 64 + 255) / 256;
        spmm_atomic_kernel<<<blocks, 256, 0, stream>>>(x, row, col, val, out, n_edges);
        return;
    }

    char* ws = (char*)d_ws;
    int* cursor  = (int*)(ws);
    int* offsets = (int*)(ws + 0x40000);
    int* bsums   = (int*)(ws + 0x80100);
    int* eidx    = (int*)(ws + 0x100000);

    hipMemsetAsync(cursor, 0, N_NODES * sizeof(int), stream);

    int e4b = ((n_edges + 3) / 4 + 255) / 256;
    hist_kernel<<<e4b, 256, 0, stream>>>(row, cursor, n_edges);
    scan_local_kernel<<<N_NODES / 256, 256, 0, stream>>>(cursor, offsets, bsums);
    scan_bsums_kernel<<<1, 256, 0, stream>>>(bsums);
    scan_add_kernel<<<N_NODES / 256, 256, 0, stream>>>(offsets, bsums, cursor, n_edges);

    int eb = (n_edges + 255) / 256;
    scatter_kernel<<<eb, 256, 0, stream>>>(row, cursor, eidx, n_edges);

    int rb = (N_NODES * 64 + 255) / 256;    // 4 rows (waves) per 256-thread block
    spmm_csr_kernel<<<rb, 256, 0, stream>>>(x, offsets, eidx, col, val, out);
}